// Round 6
// baseline (234.950 us; speedup 1.0000x reference)
//
#include <hip/hip_runtime.h>

// VQ nearest-embedding, flash-style: x persistent in registers, e streamed.
// score = x.e - 0.5||e||^2 (acc init = -0.5||e||^2), argmax == argmin dist.
// MFMA 32x32x16_f16, 3-pass hi/lo split (exact to ~2e-7).
// This round: 8 waves x 32 rows (Nt=1), 2 waves/SIMD for MFMA/LDS overlap.
// A-frag: lane l -> code_local = Mt*32+(l&31), d-block = ks*2+(l>>5).
// C/D: col = lane&31 = x-row, row = (reg&3)+8*(reg>>2)+4*(lane>>5) = code_local.
// e image (16B units): tile*2048 + code*32 + (dblk ^ (code&31)) — conflict-free
// (measured 0 conflicts in r5); DMA copies the image linearly.

typedef _Float16 half8 __attribute__((ext_vector_type(8)));
typedef float f32x4v __attribute__((ext_vector_type(4)));
typedef float f32x16 __attribute__((ext_vector_type(16)));
typedef const __attribute__((address_space(1))) unsigned int* gp_t;
typedef __attribute__((address_space(3))) unsigned int* lp_t;

#define K_DIM 1024
#define D_DIM 256

// emb f32 [256 d][1024 k] -> per-di partial norms nhp[8][1024] + fp16 hi/lo
// images in the exact main-loop LDS byte order. Coalesced, no atomics.
__global__ __launch_bounds__(256) void vq_prep(const float* __restrict__ emb,
                                               float* __restrict__ nhp,
                                               char* __restrict__ eimg_h,
                                               char* __restrict__ eimg_l) {
  __shared__ float tile[32][66];
  const int t = threadIdx.x;
  const int ki = blockIdx.x >> 3, di = blockIdx.x & 7;
  const int d0 = di * 32, k0 = ki * 64;
#pragma unroll
  for (int r = 0; r < 4; ++r) {
    int slot = r * 256 + t;            // 32 d-rows x 32 float2
    int dr = slot >> 5, c2 = slot & 31;
    float2 v = *(const float2*)(emb + (size_t)(d0 + dr) * K_DIM + k0 + c2 * 2);
    *(float2*)&tile[dr][c2 * 2] = v;
  }
  __syncthreads();
  const int codeL = t >> 2, q = t & 3;  // code-local 0..63, dblk-quarter
  half8 hh, ll;
  float s = 0.f;
#pragma unroll
  for (int j = 0; j < 8; ++j) {
    float v = tile[q * 8 + j][codeL];
    _Float16 h = (_Float16)v;
    hh[j] = h;
    ll[j] = (_Float16)(v - (float)h);
    s = fmaf(v, v, s);
  }
  const int dblk = di * 4 + q;                   // 0..31
  const int phys = dblk ^ (codeL & 31);
  const size_t off = (size_t)ki * 32768 + codeL * 512 + phys * 16;
  *(half8*)(eimg_h + off) = hh;
  *(half8*)(eimg_l + off) = ll;
  s += __shfl_xor(s, 1);
  s += __shfl_xor(s, 2);
  if (q == 0) nhp[di * K_DIM + k0 + codeL] = s;  // partial over 32 d
}

// e-tile DMA: 64 KiB (h+l) per tile, 8 instrs/thread at 512 threads
#define STAGE(tile_i, bufsel)                                                 \
  {                                                                           \
    const size_t tb = (size_t)(tile_i) * 32768 + t * 16;                      \
    _Pragma("unroll") for (int r = 0; r < 4; ++r) {                           \
      __builtin_amdgcn_global_load_lds((gp_t)(eimg_h + tb + r * 8192),        \
                                       (lp_t)(ebuf_h[bufsel] + t * 16 +       \
                                              r * 8192),                      \
                                       16, 0, 0);                             \
      __builtin_amdgcn_global_load_lds((gp_t)(eimg_l + tb + r * 8192),        \
                                       (lp_t)(ebuf_l[bufsel] + t * 16 +       \
                                              r * 8192),                      \
                                       16, 0, 0);                             \
    }                                                                         \
  }

// x chunk DMA: 8 d-rows x 256 n f32 (8 KiB), 1 instr/thread
#define XSTAGE(ci, xb_sel)                                                    \
  __builtin_amdgcn_global_load_lds(                                           \
      (gp_t)(xb + (size_t)((ci) * 8 + (t >> 6)) * K_DIM + (t & 63) * 4),      \
      (lp_t)((char*)x_lds + (xb_sel) * 8192 + t * 16), 16, 0, 0)

__global__ __launch_bounds__(512, 2) void vq_main(
    const float* __restrict__ x, const float* __restrict__ emb,
    const float* __restrict__ nhp, const char* __restrict__ eimg_h,
    const char* __restrict__ eimg_l, float* __restrict__ out,
    float* __restrict__ aout) {
  __shared__ __align__(16) char ebuf_h[2][32768];
  __shared__ __align__(16) char ebuf_l[2][32768];
  __shared__ __align__(16) float x_lds[2][8][256];  // 16 KiB dbuf
  __shared__ float nh_s[1024];                      // stores NEGATED 0.5||e||^2
  __shared__ int bk_s[256];

  const int t = threadIdx.x;  // 0..511
  const int w = t >> 6, l = t & 63, lr = l & 31, lhi = l >> 5;
  const int b = blockIdx.x >> 2;
  const int hw0 = (blockIdx.x & 3) * 256;
  const float* xb = x + (size_t)b * D_DIM * K_DIM + hw0;
  const int myrow = w * 32 + lr;  // this lane's x-row (0..255)

  // -0.5*||e||^2 from partials (coalesced)
#pragma unroll
  for (int i = 0; i < 2; ++i) {
    int c = i * 512 + t;
    float s = 0.f;
#pragma unroll
    for (int p = 0; p < 8; ++p) s += nhp[p * K_DIM + c];
    nh_s[c] = -0.5f * s;
  }

  STAGE(0, 0);    // e tile-0 DMA overlaps the x prologue
  XSTAGE(0, 0);   // x chunk-0

  // ---- x prologue: 32 chunks of 8 d, double-buffered DMA; lanes with
  // lhi == (ci&1) own chunk ci's d-range (frag elems j: d = ks*16+lhi*8+j)
  half8 Bh[16], Bl[16];
#pragma unroll
  for (int ci = 0; ci < 32; ++ci) {
    __syncthreads();  // drains XSTAGE(ci) (and STAGE(0) on ci==0)
    if (ci < 31) XSTAGE(ci + 1, (ci + 1) & 1);
    if (lhi == (ci & 1)) {
      const int ks = ci >> 1;
      half8 hv, lv;
#pragma unroll
      for (int j = 0; j < 8; ++j) {
        float v = x_lds[ci & 1][j][myrow];
        _Float16 h = (_Float16)v;
        hv[j] = h;
        lv[j] = (_Float16)(v - (float)h);
      }
      Bh[ks] = hv;
      Bl[ks] = lv;
    }
  }

  float bestv = -3.4e38f;
  int bestk = 0;

  // ---- tile loop: 16 tiles x 64 codes, full D per tile
  for (int ti = 0; ti < 16; ++ti) {
    const int buf = ti & 1;
    if (ti < 15) STAGE(ti + 1, buf ^ 1);
    // acc init = -0.5||e||^2 (nh_s pre-negated)
    f32x16 acc[2];
#pragma unroll
    for (int Mt = 0; Mt < 2; ++Mt)
#pragma unroll
      for (int rg = 0; rg < 4; ++rg) {
        f32x4v nv = *(const f32x4v*)&nh_s[ti * 64 + Mt * 32 + rg * 8 + lhi * 4];
#pragma unroll
        for (int j = 0; j < 4; ++j) acc[Mt][rg * 4 + j] = nv[j];
      }
    // K loop: A from LDS (4 b128/ks), B from registers, 6 MFMA/ks
#pragma unroll
    for (int ks = 0; ks < 16; ++ks) {
      const int po = ((ks * 2 + lhi) ^ lr) * 16;
      half8 Ah0 = *(const half8*)(ebuf_h[buf] + lr * 512 + po);
      half8 Ah1 = *(const half8*)(ebuf_h[buf] + 16384 + lr * 512 + po);
      half8 Al0 = *(const half8*)(ebuf_l[buf] + lr * 512 + po);
      half8 Al1 = *(const half8*)(ebuf_l[buf] + 16384 + lr * 512 + po);
      __builtin_amdgcn_s_setprio(1);
      acc[0] = __builtin_amdgcn_mfma_f32_32x32x16_f16(Ah0, Bh[ks], acc[0], 0, 0, 0);
      acc[1] = __builtin_amdgcn_mfma_f32_32x32x16_f16(Ah1, Bh[ks], acc[1], 0, 0, 0);
      acc[0] = __builtin_amdgcn_mfma_f32_32x32x16_f16(Al0, Bh[ks], acc[0], 0, 0, 0);
      acc[1] = __builtin_amdgcn_mfma_f32_32x32x16_f16(Al1, Bh[ks], acc[1], 0, 0, 0);
      acc[0] = __builtin_amdgcn_mfma_f32_32x32x16_f16(Ah0, Bl[ks], acc[0], 0, 0, 0);
      acc[1] = __builtin_amdgcn_mfma_f32_32x32x16_f16(Ah1, Bl[ks], acc[1], 0, 0, 0);
      __builtin_amdgcn_s_setprio(0);
    }
    // fold (codes ascend in reg within a lane; strict > == np first-min ties)
#pragma unroll
    for (int Mt = 0; Mt < 2; ++Mt)
#pragma unroll
      for (int reg = 0; reg < 16; ++reg) {
        int code = ti * 64 + Mt * 32 + (reg & 3) + 8 * (reg >> 2) + 4 * lhi;
        float v = acc[Mt][reg];
        if (v > bestv || (v == bestv && code < bestk)) {
          bestv = v;
          bestk = code;
        }
      }
    __syncthreads();  // buf reads done; drains next-tile DMA (issued tile-start)
  }

  // ---- epilogue: combine lhi halves (same row, disjoint codes)
  {
    float ov = __shfl_xor(bestv, 32);
    int ok = __shfl_xor(bestk, 32);
    if (ov > bestv || (ov == bestv && ok < bestk)) {
      bestv = ov;
      bestk = ok;
    }
    if (lhi == 0) {
      bk_s[myrow] = bestk;
      aout[(size_t)blockIdx.x * 256 + myrow] = (float)bestk;
    }
  }
  __syncthreads();
  // gather winning codes (bit-exact f32 emb rows), 1KB-coalesced stores
  const int dgrp = t >> 6, n4 = (t & 63) * 4;
  const int kk0 = bk_s[n4], kk1 = bk_s[n4 + 1], kk2 = bk_s[n4 + 2],
            kk3 = bk_s[n4 + 3];
#pragma unroll 4
  for (int i = 0; i < 32; ++i) {
    int d = i * 8 + dgrp;
    const float* er = emb + (size_t)d * K_DIM;
    float4 v = {er[kk0], er[kk1], er[kk2], er[kk3]};
    *(float4*)(out + ((size_t)b * D_DIM + d) * K_DIM + hw0 + n4) = v;
  }
}

extern "C" void kernel_launch(void* const* d_in, const int* in_sizes, int n_in,
                              void* d_out, int out_size, void* d_ws,
                              size_t ws_size, hipStream_t stream) {
  const float* x = (const float*)d_in[0];
  const float* emb = (const float*)d_in[1];
  float* out = (float*)d_out;
  float* aout = out + (size_t)64 * 256 * 32 * 32;  // 16777216
  float* nhp = (float*)d_ws;                       // 8*1024 f32 partial norms
  char* eimg_h = (char*)d_ws + 32768;              // 512 KiB
  char* eimg_l = eimg_h + 524288;                  // 512 KiB
  vq_prep<<<128, 256, 0, stream>>>(emb, nhp, eimg_h, eimg_l);
  vq_main<<<256, 512, 0, stream>>>(x, emb, nhp, eimg_h, eimg_l, out, aout);
}

// Round 7
// 226.602 us; speedup vs baseline: 1.0368x; 1.0368x over previous
//
#include <hip/hip_runtime.h>

// VQ nearest-embedding, flash-style + 8-phase counted-vmcnt schedule (T3+T4+T5).
// score = x.e - 0.5||e||^2 (acc init = -0.5||e||^2), argmax == argmin dist.
// MFMA 32x32x16_f16, 3-pass hi/lo split (exact to ~2e-7).
// A-frag: lane l -> code_local = Mt*32+(l&31), d-block = ks*2+(l>>5).
// C/D: col = lane&31 = x-row, row = (reg&3)+8*(reg>>2)+4*(lane>>5) = code_local.
// e image (16B units): tile*2048 + code*32 + (dblk ^ (code&31)) — conflict-free
// (0 conflicts measured r5/r6); DMA copies the image linearly.
// Schedule: raw s_barrier only; vmcnt never drained inside the tile compute —
// next-tile DMA (1 instr/phase) flies across the whole tile, waited at the
// NEXT tile's top (issued ~8K cyc earlier). Per phase: 8 ds_read_b128 ->
// barrier -> lgkmcnt(0) -> setprio(1) 12 MFMA setprio(0) -> barrier.

typedef _Float16 half8 __attribute__((ext_vector_type(8)));
typedef float f32x4v __attribute__((ext_vector_type(4)));
typedef float f32x16 __attribute__((ext_vector_type(16)));
typedef const __attribute__((address_space(1))) unsigned int* gp_t;
typedef __attribute__((address_space(3))) unsigned int* lp_t;

#define K_DIM 1024
#define D_DIM 256

#define MFMA32(A, B, C) __builtin_amdgcn_mfma_f32_32x32x16_f16(A, B, C, 0, 0, 0)

// emb f32 [256 d][1024 k] -> per-di partial norms nhp[8][1024] + fp16 hi/lo
// images in the exact main-loop LDS byte order. Coalesced, no atomics.
__global__ __launch_bounds__(256) void vq_prep(const float* __restrict__ emb,
                                               float* __restrict__ nhp,
                                               char* __restrict__ eimg_h,
                                               char* __restrict__ eimg_l) {
  __shared__ float tile[32][66];
  const int t = threadIdx.x;
  const int ki = blockIdx.x >> 3, di = blockIdx.x & 7;
  const int d0 = di * 32, k0 = ki * 64;
#pragma unroll
  for (int r = 0; r < 4; ++r) {
    int slot = r * 256 + t;            // 32 d-rows x 32 float2
    int dr = slot >> 5, c2 = slot & 31;
    float2 v = *(const float2*)(emb + (size_t)(d0 + dr) * K_DIM + k0 + c2 * 2);
    *(float2*)&tile[dr][c2 * 2] = v;
  }
  __syncthreads();
  const int codeL = t >> 2, q = t & 3;  // code-local 0..63, dblk-quarter
  half8 hh, ll;
  float s = 0.f;
#pragma unroll
  for (int j = 0; j < 8; ++j) {
    float v = tile[q * 8 + j][codeL];
    _Float16 h = (_Float16)v;
    hh[j] = h;
    ll[j] = (_Float16)(v - (float)h);
    s = fmaf(v, v, s);
  }
  const int dblk = di * 4 + q;                   // 0..31
  const int phys = dblk ^ (codeL & 31);
  const size_t off = (size_t)ki * 32768 + codeL * 512 + phys * 16;
  *(half8*)(eimg_h + off) = hh;
  *(half8*)(eimg_l + off) = ll;
  s += __shfl_xor(s, 1);
  s += __shfl_xor(s, 2);
  if (q == 0) nhp[di * K_DIM + k0 + codeL] = s;  // partial over 32 d
}

// full e-tile DMA (prologue only): 64 KiB (h+l), 8 instrs/thread
#define STAGE(tile_i, bufsel)                                                 \
  {                                                                           \
    const size_t tb = (size_t)(tile_i) * 32768 + t * 16;                      \
    _Pragma("unroll") for (int r = 0; r < 4; ++r) {                           \
      __builtin_amdgcn_global_load_lds((gp_t)(eimg_h + tb + r * 8192),        \
                                       (lp_t)(ebuf_h[bufsel] + t * 16 +       \
                                              r * 8192),                      \
                                       16, 0, 0);                             \
      __builtin_amdgcn_global_load_lds((gp_t)(eimg_l + tb + r * 8192),        \
                                       (lp_t)(ebuf_l[bufsel] + t * 16 +       \
                                              r * 8192),                      \
                                       16, 0, 0);                             \
    }                                                                         \
  }

// one-eighth of an e-tile DMA: phase q of 8 (q<4: h chunk q, else l chunk q-4)
#define STAGE1(tile_i, bufsel, q)                                             \
  {                                                                           \
    const size_t tb = (size_t)(tile_i) * 32768 + t * 16;                      \
    if ((q) < 4) {                                                            \
      __builtin_amdgcn_global_load_lds((gp_t)(eimg_h + tb + (q) * 8192),      \
                                       (lp_t)(ebuf_h[bufsel] + t * 16 +       \
                                              (q) * 8192),                    \
                                       16, 0, 0);                             \
    } else {                                                                  \
      __builtin_amdgcn_global_load_lds(                                       \
          (gp_t)(eimg_l + tb + ((q) - 4) * 8192),                             \
          (lp_t)(ebuf_l[bufsel] + t * 16 + ((q) - 4) * 8192), 16, 0, 0);      \
    }                                                                         \
  }

// x chunk buffers (4 x 16 KiB) alias ebuf[1], free during the x prologue
#define XBUF(q) \
  ((q) < 2 ? (ebuf_h[1] + (q) * 16384) : (ebuf_l[1] + ((q) - 2) * 16384))

// x chunk DMA: 16 d-rows x 256 n f32 (16 KiB), 2 instrs/thread
#define XSTAGE(ci, q)                                                         \
  {                                                                           \
    _Pragma("unroll") for (int r = 0; r < 2; ++r) {                           \
      int slot = r * 512 + t;                                                 \
      __builtin_amdgcn_global_load_lds(                                       \
          (gp_t)(xb + (size_t)((ci) * 16 + (slot >> 6)) * K_DIM +             \
                 (slot & 63) * 4),                                            \
          (lp_t)(XBUF(q) + slot * 16), 16, 0, 0);                             \
    }                                                                         \
  }

#define SBAR() __builtin_amdgcn_s_barrier()
#define SCHED0() __builtin_amdgcn_sched_barrier(0)

__global__ __launch_bounds__(512, 2) void vq_main(
    const float* __restrict__ x, const float* __restrict__ emb,
    const float* __restrict__ nhp, const char* __restrict__ eimg_h,
    const char* __restrict__ eimg_l, float* __restrict__ out,
    float* __restrict__ aout) {
  __shared__ __align__(16) char ebuf_h[2][32768];
  __shared__ __align__(16) char ebuf_l[2][32768];
  __shared__ float nh_s[1024];  // NEGATED 0.5||e||^2
  __shared__ int bk_s[256];

  const int t = threadIdx.x;  // 0..511
  const int w = t >> 6, l = t & 63, lr = l & 31, lhi = l >> 5;
  const int b = blockIdx.x >> 2;
  const int hw0 = (blockIdx.x & 3) * 256;
  const float* xb = x + (size_t)b * D_DIM * K_DIM + hw0;
  const int myrow = w * 32 + lr;  // this lane's x-row (0..255)

  // -0.5*||e||^2 from partials (coalesced)
#pragma unroll
  for (int i = 0; i < 2; ++i) {
    int c = i * 512 + t;
    float s = 0.f;
#pragma unroll
    for (int p = 0; p < 8; ++p) s += nhp[p * K_DIM + c];
    nh_s[c] = -0.5f * s;
  }

  // ---- x prologue: 16 chunks of 16 d, depth-3 prefetch into 4 buffers
  XSTAGE(0, 0);
  XSTAGE(1, 1);
  XSTAGE(2, 2);
  STAGE(0, 0);  // e tile-0 rides behind the x pipeline
  half8 Bh[16], Bl[16];
#pragma unroll
  for (int ci = 0; ci < 16; ++ci) {
    asm volatile("s_waitcnt vmcnt(4)" ::: "memory");  // chunk ci landed
    SCHED0();
    SBAR();  // all waves' DMA for ci landed; all done converting ci-1
    SCHED0();
    if (ci + 3 < 16) XSTAGE(ci + 3, (ci + 3) & 3);  // overwrites buf of ci-1
    const float* xsf = (const float*)XBUF(ci & 3);
    half8 hv, lv;
#pragma unroll
    for (int j = 0; j < 8; ++j) {
      float v = xsf[(lhi * 8 + j) * 256 + myrow];
      _Float16 h = (_Float16)v;
      hv[j] = h;
      lv[j] = (_Float16)(v - (float)h);
    }
    Bh[ci] = hv;
    Bl[ci] = lv;
  }

  float bestv = -3.4e38f;
  int bestk = 0;

  // ---- tile loop: 16 tiles x 64 codes, 8 phases x 2 ks per tile
  for (int ti = 0; ti < 16; ++ti) {
    const int buf = ti & 1;
    asm volatile("s_waitcnt vmcnt(0)" ::: "memory");  // STAGE(ti): issued a tile ago
    SCHED0();
    SBAR();  // buffer swap point: everyone done reading buf^1, DMA of buf landed
    SCHED0();
    const char* bh0 = ebuf_h[buf];
    const char* bl0 = ebuf_l[buf];
    const int tn = (ti + 1) & 15;  // ti==15 stages tile 0 (unread, harmless)
    f32x16 acc[2];
#pragma unroll
    for (int Mt = 0; Mt < 2; ++Mt)
#pragma unroll
      for (int rg = 0; rg < 4; ++rg) {
        f32x4v nv = *(const f32x4v*)&nh_s[ti * 64 + Mt * 32 + rg * 8 + lhi * 4];
#pragma unroll
        for (int j = 0; j < 4; ++j) acc[Mt][rg * 4 + j] = nv[j];
      }
#pragma unroll
    for (int ph = 0; ph < 8; ++ph) {
      const int ks0 = ph * 2, ks1 = ph * 2 + 1;
      const int poa = ((ks0 * 2 + lhi) ^ lr) * 16;
      const int pob = ((ks1 * 2 + lhi) ^ lr) * 16;
      half8 Ah0a = *(const half8*)(bh0 + lr * 512 + poa);
      half8 Ah1a = *(const half8*)(bh0 + 16384 + lr * 512 + poa);
      half8 Al0a = *(const half8*)(bl0 + lr * 512 + poa);
      half8 Al1a = *(const half8*)(bl0 + 16384 + lr * 512 + poa);
      half8 Ah0b = *(const half8*)(bh0 + lr * 512 + pob);
      half8 Ah1b = *(const half8*)(bh0 + 16384 + lr * 512 + pob);
      half8 Al0b = *(const half8*)(bl0 + lr * 512 + pob);
      half8 Al1b = *(const half8*)(bl0 + 16384 + lr * 512 + pob);
      STAGE1(tn, buf ^ 1, ph);  // 1/8 of next tile, in flight across phases
      SBAR();
      asm volatile("s_waitcnt lgkmcnt(0)" ::: "memory");
      SCHED0();
      __builtin_amdgcn_s_setprio(1);
      acc[0] = MFMA32(Ah0a, Bh[ks0], acc[0]);
      acc[1] = MFMA32(Ah1a, Bh[ks0], acc[1]);
      acc[0] = MFMA32(Al0a, Bh[ks0], acc[0]);
      acc[1] = MFMA32(Al1a, Bh[ks0], acc[1]);
      acc[0] = MFMA32(Ah0a, Bl[ks0], acc[0]);
      acc[1] = MFMA32(Ah1a, Bl[ks0], acc[1]);
      acc[0] = MFMA32(Ah0b, Bh[ks1], acc[0]);
      acc[1] = MFMA32(Ah1b, Bh[ks1], acc[1]);
      acc[0] = MFMA32(Al0b, Bh[ks1], acc[0]);
      acc[1] = MFMA32(Al1b, Bh[ks1], acc[1]);
      acc[0] = MFMA32(Ah0b, Bl[ks1], acc[0]);
      acc[1] = MFMA32(Ah1b, Bl[ks1], acc[1]);
      __builtin_amdgcn_s_setprio(0);
      SCHED0();
      SBAR();
    }
    // fold (codes ascend; strict > == np first-min tie rule)
#pragma unroll
    for (int Mt = 0; Mt < 2; ++Mt)
#pragma unroll
      for (int reg = 0; reg < 16; ++reg) {
        int code = ti * 64 + Mt * 32 + (reg & 3) + 8 * (reg >> 2) + 4 * lhi;
        float v = acc[Mt][reg];
        if (v > bestv || (v == bestv && code < bestk)) {
          bestv = v;
          bestk = code;
        }
      }
  }

  // ---- epilogue: combine lhi halves (same row, disjoint codes)
  {
    float ov = __shfl_xor(bestv, 32);
    int ok = __shfl_xor(bestk, 32);
    if (ov > bestv || (ov == bestv && ok < bestk)) {
      bestv = ov;
      bestk = ok;
    }
    if (lhi == 0) {
      bk_s[myrow] = bestk;
      aout[(size_t)blockIdx.x * 256 + myrow] = (float)bestk;
    }
  }
  __syncthreads();  // full drain (incl. dangling tile-0 DMA) + bk_s visible
  // gather winning codes (bit-exact f32 emb rows), 1KB-coalesced stores
  const int dgrp = t >> 6, n4 = (t & 63) * 4;
  const int kk0 = bk_s[n4], kk1 = bk_s[n4 + 1], kk2 = bk_s[n4 + 2],
            kk3 = bk_s[n4 + 3];
#pragma unroll 4
  for (int i = 0; i < 32; ++i) {
    int d = i * 8 + dgrp;
    const float* er = emb + (size_t)d * K_DIM;
    float4 v = {er[kk0], er[kk1], er[kk2], er[kk3]};
    *(float4*)(out + ((size_t)b * D_DIM + d) * K_DIM + hw0 + n4) = v;
  }
}

extern "C" void kernel_launch(void* const* d_in, const int* in_sizes, int n_in,
                              void* d_out, int out_size, void* d_ws,
                              size_t ws_size, hipStream_t stream) {
  const float* x = (const float*)d_in[0];
  const float* emb = (const float*)d_in[1];
  float* out = (float*)d_out;
  float* aout = out + (size_t)64 * 256 * 32 * 32;  // 16777216
  float* nhp = (float*)d_ws;                       // 8*1024 f32 partial norms
  char* eimg_h = (char*)d_ws + 32768;              // 512 KiB
  char* eimg_l = eimg_h + 524288;                  // 512 KiB
  vq_prep<<<128, 256, 0, stream>>>(emb, nhp, eimg_h, eimg_l);
  vq_main<<<256, 512, 0, stream>>>(x, emb, nhp, eimg_h, eimg_l, out, aout);
}